// Round 5
// baseline (199.550 us; speedup 1.0000x reference)
//
#include <hip/hip_runtime.h>
#include <hip/hip_bf16.h>

// Problem constants (fixed by reference)
#define B_  4
#define E_  100000
#define N_  10000
#define NR_ 6
#define H_  256
#define D_  256
#define OUT_ 128

typedef __attribute__((ext_vector_type(4))) float f32x4;
typedef __attribute__((ext_vector_type(8))) short bf16x8;

__device__ __forceinline__ ushort f2bf(float f) {
  unsigned u = __builtin_bit_cast(unsigned, f);
  u += 0x7fffu + ((u >> 16) & 1u);  // round-to-nearest-even
  return (ushort)(u >> 16);
}

// ---------------------------------------------------------------------------
// Fused kernel: histogram (blocks 0..390) + weight packing (blocks 391..534).
// Weight packing: f32 [K][C] -> bf16 MFMA B-fragment order
//   Wp[l][nb][ks][lane][8], elem = W_l[ks*32+(lane>>4)*8+j][nb*16+(lane&15)]
// ---------------------------------------------------------------------------
__global__ __launch_bounds__(256) void hist_convert_kernel(
    const int* __restrict__ idx, int* __restrict__ counts,
    const float* __restrict__ W_up, const float* __restrict__ Ws,
    const float* __restrict__ W_out, ushort* __restrict__ Wp) {
  if (blockIdx.x < 391) {
    const int e = blockIdx.x * 256 + threadIdx.x;
    if (e < E_) atomicAdd(&counts[idx[e]], 1);
    return;
  }
  const int g = (blockIdx.x - 391) * 256 + threadIdx.x;  // < 36864
  int l, goff, Ncols;
  if (g < 32768) { l = g >> 13; goff = g & 8191; Ncols = 256; }
  else           { l = 4;       goff = g - 32768; Ncols = 128; }
  const float* src = (l == 0) ? W_up : (l < 4 ? Ws + (l - 1) * 65536 : W_out);
  const int lane = goff & 63;
  const int ks   = (goff >> 6) & 7;
  const int nb   = goff >> 9;
  const int col  = nb * 16 + (lane & 15);
  const int k0   = ks * 32 + (lane >> 4) * 8;
  ushort tmp[8];
#pragma unroll
  for (int j = 0; j < 8; ++j)
    tmp[j] = f2bf(src[(size_t)(k0 + j) * Ncols + col]);
  *reinterpret_cast<uint4*>(&Wp[(size_t)g * 8]) =
      *reinterpret_cast<const uint4*>(tmp);
}

__global__ __launch_bounds__(1024) void scan_kernel(
    const int* __restrict__ counts, int* __restrict__ starts,
    int* __restrict__ cursor) {
  __shared__ int sums[1024];
  const int t = threadIdx.x;
  const int base = t * 10;
  int loc[10];
  int s = 0;
#pragma unroll
  for (int j = 0; j < 10; ++j) {
    int v = (base + j < N_) ? counts[base + j] : 0;
    loc[j] = v;
    s += v;
  }
  sums[t] = s;
  __syncthreads();
  for (int off = 1; off < 1024; off <<= 1) {
    int v = (t >= off) ? sums[t - off] : 0;
    __syncthreads();
    sums[t] += v;
    __syncthreads();
  }
  int run = sums[t] - s;  // exclusive prefix
#pragma unroll
  for (int j = 0; j < 10; ++j) {
    if (base + j < N_) {
      starts[base + j] = run;
      cursor[base + j] = run;
      run += loc[j];
    }
  }
}

__global__ __launch_bounds__(256) void fill_kernel(const int* __restrict__ idx,
                                                   int* __restrict__ cursor,
                                                   int* __restrict__ buckets) {
  int e = blockIdx.x * 256 + threadIdx.x;
  if (e < E_) {
    int pos = atomicAdd(&cursor[idx[e]], 1);
    buckets[pos] = e;
  }
}

// ---------------------------------------------------------------------------
// Gather v3: block = 4 nodes, wave = one node, lane owns float4 h-chunk
// (h0 = lane*4), loops all 4 batches internally. rp computed ONCE per
// edge per lane; 4 independent x loads per edge (ILP). No barriers.
// ---------------------------------------------------------------------------
__global__ __launch_bounds__(256) void gather_kernel(
    const float* __restrict__ x, const float* __restrict__ rbf,
    const float* __restrict__ W_rbf, const int* __restrict__ starts,
    const int* __restrict__ counts, const int* __restrict__ buckets,
    ushort* __restrict__ agg) {
  const int tid = threadIdx.x;
  const int node = blockIdx.x * 4 + (tid >> 6);
  const int lane = tid & 63;
  const int h0 = lane * 4;

  f32x4 wrv[NR_];
#pragma unroll
  for (int r = 0; r < NR_; ++r)
    wrv[r] = *reinterpret_cast<const f32x4*>(&W_rbf[r * H_ + h0]);

  f32x4 acc[B_] = {};
  const int s = starts[node];
  const int d = counts[node];

#pragma unroll 2
  for (int j = 0; j < d; ++j) {
    const int e = buckets[s + j];
    f32x4 rp = {0.f, 0.f, 0.f, 0.f};
#pragma unroll
    for (int r = 0; r < NR_; ++r) rp += rbf[e * NR_ + r] * wrv[r];
#pragma unroll
    for (int b = 0; b < B_; ++b) {
      const f32x4 xv = *reinterpret_cast<const f32x4*>(
          &x[((size_t)b * E_ + e) * H_ + h0]);
      acc[b] += xv * rp;
    }
  }

#pragma unroll
  for (int b = 0; b < B_; ++b) {
    ushort4 o;
    o.x = f2bf(acc[b].x); o.y = f2bf(acc[b].y);
    o.z = f2bf(acc[b].z); o.w = f2bf(acc[b].w);
    *reinterpret_cast<ushort4*>(&agg[((size_t)b * N_ + node) * H_ + h0]) = o;
  }
}

// ---------------------------------------------------------------------------
// Fused 5-layer chain: BM=64 rows/block, 512 thr (8 waves, 2x4).
// act [64][256] bf16 in LDS, XOR-swizzled (byte ^= (row&7)<<4).
// B-frags stream coalesced from pre-packed L2-resident weights.
// ---------------------------------------------------------------------------
__global__ __launch_bounds__(512) void chain_kernel(
    const ushort* __restrict__ agg, const ushort* __restrict__ Wp,
    const float* __restrict__ bs, float* __restrict__ out) {
  __shared__ ushort act[64 * 256];  // 32 KB
  char* actb = reinterpret_cast<char*>(act);
  const int row0 = blockIdx.x * 64;
  const int tid = threadIdx.x;
  const int wave = tid >> 6;
  const int lane = tid & 63;
  const int lr = lane & 15;
  const int lq = lane >> 4;
  const int wr = wave >> 2;  // 0..1 : 32-row strip
  const int wc = wave & 3;   // 0..3 : 64-col strip (32-col on final)

  // --- stage agg tile into LDS, swizzled ---
#pragma unroll
  for (int t = 0; t < 4; ++t) {
    const int idx = tid + t * 512;  // 16B-chunk id, 0..2047
    const int row = idx >> 5;
    const int s = idx & 31;
    const uint4 v = *reinterpret_cast<const uint4*>(
        &agg[(size_t)(row0 + row) * 256 + s * 8]);
    const int byte = (row * 512 + s * 16) ^ ((row & 7) << 4);
    *reinterpret_cast<uint4*>(actb + byte) = v;
  }
  __syncthreads();

  // --- layers 0..3: 256 -> 256 (l=0: W_up, no act; l>=1: silu(.+bs[l-1])) ---
  for (int l = 0; l < 4; ++l) {
    const ushort* W = Wp + l * 65536;
    f32x4 acc[2][4] = {};
#pragma unroll
    for (int ks = 0; ks < 8; ++ks) {
      bf16x8 af[2], bfr[4];
#pragma unroll
      for (int m = 0; m < 2; ++m) {
        const int row = wr * 32 + m * 16 + lr;
        const int byte = (row * 512 + ks * 64 + lq * 16) ^ ((row & 7) << 4);
        af[m] = *reinterpret_cast<const bf16x8*>(actb + byte);
      }
#pragma unroll
      for (int n = 0; n < 4; ++n) {
        const int nb = wc * 4 + n;
        bfr[n] = *reinterpret_cast<const bf16x8*>(
            &W[(size_t)(((nb * 8 + ks) * 64) + lane) * 8]);
      }
#pragma unroll
      for (int m = 0; m < 2; ++m)
#pragma unroll
        for (int n = 0; n < 4; ++n)
          acc[m][n] = __builtin_amdgcn_mfma_f32_16x16x32_bf16(af[m], bfr[n],
                                                              acc[m][n], 0, 0, 0);
    }
    __syncthreads();  // all waves done READING act for this layer

    const bool ba = (l > 0);
#pragma unroll
    for (int n = 0; n < 4; ++n) {
      const int col = wc * 64 + n * 16 + lr;
      const float bv = ba ? bs[(l - 1) * 256 + col] : 0.f;
#pragma unroll
      for (int m = 0; m < 2; ++m) {
#pragma unroll
        for (int r = 0; r < 4; ++r) {
          float v = acc[m][n][r];
          if (ba) {
            v += bv;
            v = v / (1.0f + __expf(-v));  // SiLU
          }
          const int row = wr * 32 + m * 16 + lq * 4 + r;
          const int byte = (row * 512 + col * 2) ^ ((row & 7) << 4);
          *reinterpret_cast<ushort*>(actb + byte) = f2bf(v);
        }
      }
    }
    __syncthreads();  // writes visible before next layer reads
  }

  // --- final layer: 256 -> 128, f32 output. Wave tile 32 rows x 32 cols ---
  {
    const ushort* W = Wp + 4 * 65536;
    f32x4 acc[2][2] = {};
#pragma unroll
    for (int ks = 0; ks < 8; ++ks) {
      bf16x8 af[2], bfr[2];
#pragma unroll
      for (int m = 0; m < 2; ++m) {
        const int row = wr * 32 + m * 16 + lr;
        const int byte = (row * 512 + ks * 64 + lq * 16) ^ ((row & 7) << 4);
        af[m] = *reinterpret_cast<const bf16x8*>(actb + byte);
      }
#pragma unroll
      for (int n = 0; n < 2; ++n) {
        const int nb = wc * 2 + n;
        bfr[n] = *reinterpret_cast<const bf16x8*>(
            &W[(size_t)(((nb * 8 + ks) * 64) + lane) * 8]);
      }
#pragma unroll
      for (int m = 0; m < 2; ++m)
#pragma unroll
        for (int n = 0; n < 2; ++n)
          acc[m][n] = __builtin_amdgcn_mfma_f32_16x16x32_bf16(af[m], bfr[n],
                                                              acc[m][n], 0, 0, 0);
    }
#pragma unroll
    for (int m = 0; m < 2; ++m)
#pragma unroll
      for (int n = 0; n < 2; ++n)
#pragma unroll
        for (int r = 0; r < 4; ++r) {
          const int row = row0 + wr * 32 + m * 16 + lq * 4 + r;
          const int col = wc * 32 + n * 16 + lr;
          out[(size_t)row * OUT_ + col] = acc[m][n][r];
        }
  }
}

// ---------------------------------------------------------------------------
extern "C" void kernel_launch(void* const* d_in, const int* in_sizes, int n_in,
                              void* d_out, int out_size, void* d_ws,
                              size_t ws_size, hipStream_t stream) {
  const float* x     = (const float*)d_in[0];  // [B,E,H]
  const float* rbf   = (const float*)d_in[1];  // [E,NR]
  const int*   idx   = (const int*)d_in[2];    // [E]
  const float* W_rbf = (const float*)d_in[3];  // [NR,H]
  const float* W_up  = (const float*)d_in[4];  // [H,D]
  const float* Ws    = (const float*)d_in[5];  // [L,D,D]
  const float* bs    = (const float*)d_in[6];  // [L,D]
  const float* W_out = (const float*)d_in[7];  // [D,OUT]
  float* out = (float*)d_out;                  // [B,N,OUT] f32

  // workspace layout (bytes)
  char* ws = (char*)d_ws;
  const size_t agg_bytes = (size_t)B_ * N_ * H_ * sizeof(ushort);  // 20.48 MB
  ushort* agg = (ushort*)(ws);
  ushort* Wp  = (ushort*)(ws + agg_bytes);  // 294912 bf16
  char* ibase = ws + agg_bytes + 294912 * sizeof(ushort);
  int* counts  = (int*)(ibase);
  int* starts  = (int*)(ibase + 40000);
  int* cursor  = (int*)(ibase + 80000);
  int* buckets = (int*)(ibase + 120000);

  // zero counts, then fused hist + weight packing
  hipMemsetAsync(counts, 0, N_ * sizeof(int), stream);
  hist_convert_kernel<<<391 + 144, 256, 0, stream>>>(idx, counts, W_up, Ws,
                                                     W_out, Wp);
  scan_kernel<<<1, 1024, 0, stream>>>(counts, starts, cursor);
  fill_kernel<<<(E_ + 255) / 256, 256, 0, stream>>>(idx, cursor, buckets);

  // gather-aggregate into bf16 agg (block = 4 nodes)
  gather_kernel<<<N_ / 4, 256, 0, stream>>>(x, rbf, W_rbf, starts, counts,
                                            buckets, agg);

  // fused 5-layer chain, 40000/64 = 625 row-tiles
  chain_kernel<<<625, 512, 0, stream>>>(agg, Wp, bs, out);
}